// Round 1
// baseline (229.155 us; speedup 1.0000x reference)
//
#include <hip/hip_runtime.h>
#include <hip/hip_bf16.h>

// Fourier-KAN fused kernel for MI355X (gfx950).
// out[b,o] = bias[o] + sum_{i,g} cos((g+1)x[b,i])*c0[i,o,g] + sin((g+1)x[b,i])*c1[i,o,g]
// Treated as GEMM M=32768, N=64, K=8192 (k = i*16 + t*8 + g, t=0 cos / t=1 sin),
// A generated in-register (sincos + angle-addition recurrence), B (weights) packed
// to bf16 fragments in LDS, mfma_f32_16x16x32_bf16 accumulation.
//
// Slot-consistency trick: A-slot (h=lane>>4, j) and B-slot (h, j) use the SAME
// logical-k map k_local = ((h&1)<<4) | ((h>>1)<<3) | j, so the exact internal
// operand k-permutation of the MFMA cancels (A/B layouts are symmetric).
// C/D layout (verified): col = lane&15, row = (lane>>4)*4 + reg.

#define N_B 32768
#define N_I 512
#define N_O 64

typedef short bf16x8 __attribute__((ext_vector_type(8)));
typedef float f32x4 __attribute__((ext_vector_type(4)));

__device__ __forceinline__ int pack_bf16x2(float lo, float hi) {
    union { __hip_bfloat162 h; int i; } u;
    u.h = __float22bfloat162_rn(make_float2(lo, hi));
    return u.i;
}

// Staging task -> source float offset into coeffs (2,512,64,8), excluding the
// per-chunk advance of c*8 i's (= c*4096 floats).
__device__ __forceinline__ size_t stage_src_off(int task) {
    const int l_  = task & 63;
    const int f_  = (task >> 6) & 3;   // n-fragment 0..3
    const int k4_ = task >> 8;         // k-step within chunk 0..3
    const int h_  = l_ >> 4;           // slot group 0..3
    const int t_  = h_ >> 1;           // 0 = cos coeffs, 1 = sin coeffs
    const int io_ = h_ & 1;            // i offset within k-step
    const int i_  = k4_ * 2 + io_;     // i within chunk's 8 i's
    const int n_  = f_ * 16 + (l_ & 15);
    return ((size_t)(t_ * N_I + i_) * N_O + n_) * 8;
}

__global__ __launch_bounds__(512, 2)
void fkan_main(const float* __restrict__ X, const float* __restrict__ C,
               const float* __restrict__ bias, float* __restrict__ out) {
    // Double-buffered fragment-ordered weights: [buf][kstep(4)][nfrag(4)][lane(64)][8 bf16]
    __shared__ __align__(16) int Wl[2][4096];   // 2 x 16 KB

    const int tid  = threadIdx.x;
    const int l    = tid & 63;
    const int wm   = tid >> 6;                      // wave id 0..7 (M-stacked)
    const int row0 = (blockIdx.x << 7) + (wm << 4); // 16 rows per wave
    const int h    = l >> 4;                        // slot group
    const int hs   = h >> 1;                        // 0: cos half, 1: sin half
    const int io   = h & 1;                         // i offset within k-step

    // x pointer for this lane's (row, i-parity) stream
    const float* xptr = X + (size_t)(row0 + (l & 15)) * N_I + io;

    // per-thread weight staging sources (two tasks per thread)
    const float* srcA = C + stage_src_off(tid);
    const float* srcB = C + stage_src_off(tid + 512);

    f32x4 acc0 = {0.f, 0.f, 0.f, 0.f};
    f32x4 acc1 = acc0, acc2 = acc0, acc3 = acc0;

    float4 ra0, ra1, rb0, rb1;

    // ---- prologue: stage chunk 0 into LDS buf0, prefetch chunk 1 into regs ----
    ra0 = *(const float4*)(srcA);
    ra1 = *(const float4*)(srcA + 4);
    rb0 = *(const float4*)(srcB);
    rb1 = *(const float4*)(srcB + 4);
    {
        int4 wa = { pack_bf16x2(ra0.x, ra0.y), pack_bf16x2(ra0.z, ra0.w),
                    pack_bf16x2(ra1.x, ra1.y), pack_bf16x2(ra1.z, ra1.w) };
        int4 wb = { pack_bf16x2(rb0.x, rb0.y), pack_bf16x2(rb0.z, rb0.w),
                    pack_bf16x2(rb1.x, rb1.y), pack_bf16x2(rb1.z, rb1.w) };
        *(int4*)&Wl[0][tid * 4]         = wa;
        *(int4*)&Wl[0][(tid + 512) * 4] = wb;
    }
    ra0 = *(const float4*)(srcA + 4096);
    ra1 = *(const float4*)(srcA + 4096 + 4);
    rb0 = *(const float4*)(srcB + 4096);
    rb1 = *(const float4*)(srcB + 4096 + 4);
    __syncthreads();

    // ---- main loop over 64 K-chunks (8 i's each) ----
    #pragma unroll 1
    for (int c = 0; c < 64; ++c) {
        const int* bufR = Wl[c & 1];

        #pragma unroll
        for (int s = 0; s < 4; ++s) {
            // this lane's x value for k-step s: i = c*8 + s*2 + io
            const float xv = xptr[(c << 3) + (s << 1)];
            float s1, c1;
            __sincosf(xv, &s1, &c1);

            // angle-addition recurrence: cv[k]=cos(k*x), sv[k]=sin(k*x)
            float cv[9], sv[9];
            cv[1] = c1; sv[1] = s1;
            #pragma unroll
            for (int k = 2; k <= 8; ++k) {
                cv[k] = __builtin_fmaf(c1, cv[k-1], -(s1 * sv[k-1]));
                sv[k] = __builtin_fmaf(s1, cv[k-1],  (c1 * sv[k-1]));
            }

            // pack this lane's half (cos for h<2, sin for h>=2), freqs 1..8
            int aw0, aw1, aw2, aw3;
            {
                const int cw0 = pack_bf16x2(cv[1], cv[2]), sw0 = pack_bf16x2(sv[1], sv[2]);
                const int cw1 = pack_bf16x2(cv[3], cv[4]), sw1 = pack_bf16x2(sv[3], sv[4]);
                const int cw2 = pack_bf16x2(cv[5], cv[6]), sw2 = pack_bf16x2(sv[5], sv[6]);
                const int cw3 = pack_bf16x2(cv[7], cv[8]), sw3 = pack_bf16x2(sv[7], sv[8]);
                aw0 = hs ? sw0 : cw0;
                aw1 = hs ? sw1 : cw1;
                aw2 = hs ? sw2 : cw2;
                aw3 = hs ? sw3 : cw3;
            }
            union { int d[4]; bf16x8 v; } ua;
            ua.d[0] = aw0; ua.d[1] = aw1; ua.d[2] = aw2; ua.d[3] = aw3;
            const bf16x8 af = ua.v;

            const bf16x8 bf0 = *(const bf16x8*)&bufR[((s * 4 + 0) * 64 + l) * 4];
            acc0 = __builtin_amdgcn_mfma_f32_16x16x32_bf16(af, bf0, acc0, 0, 0, 0);
            const bf16x8 bf1 = *(const bf16x8*)&bufR[((s * 4 + 1) * 64 + l) * 4];
            acc1 = __builtin_amdgcn_mfma_f32_16x16x32_bf16(af, bf1, acc1, 0, 0, 0);
            const bf16x8 bf2 = *(const bf16x8*)&bufR[((s * 4 + 2) * 64 + l) * 4];
            acc2 = __builtin_amdgcn_mfma_f32_16x16x32_bf16(af, bf2, acc2, 0, 0, 0);
            const bf16x8 bf3 = *(const bf16x8*)&bufR[((s * 4 + 3) * 64 + l) * 4];
            acc3 = __builtin_amdgcn_mfma_f32_16x16x32_bf16(af, bf3, acc3, 0, 0, 0);
        }

        // write next chunk's weights (already in regs), prefetch chunk c+2
        if (c < 63) {
            __syncthreads();   // all waves done reading the buffer we overwrite
            int* bufW = Wl[(c + 1) & 1];
            int4 wa = { pack_bf16x2(ra0.x, ra0.y), pack_bf16x2(ra0.z, ra0.w),
                        pack_bf16x2(ra1.x, ra1.y), pack_bf16x2(ra1.z, ra1.w) };
            int4 wb = { pack_bf16x2(rb0.x, rb0.y), pack_bf16x2(rb0.z, rb0.w),
                        pack_bf16x2(rb1.x, rb1.y), pack_bf16x2(rb1.z, rb1.w) };
            *(int4*)&bufW[tid * 4]         = wa;
            *(int4*)&bufW[(tid + 512) * 4] = wb;
            if (c < 62) {
                const size_t o = (size_t)(c + 2) * 4096;
                ra0 = *(const float4*)(srcA + o);
                ra1 = *(const float4*)(srcA + o + 4);
                rb0 = *(const float4*)(srcB + o);
                rb1 = *(const float4*)(srcB + o + 4);
            }
            __syncthreads();   // buffer ready for next iteration
        }
    }

    // ---- epilogue: C/D layout col=lane&15, row=(lane>>4)*4+reg ----
    const int colb = l & 15;
    const int rr   = row0 + ((l >> 4) << 2);
    #pragma unroll
    for (int ff = 0; ff < 4; ++ff) {
        const int col = ff * 16 + colb;
        const float bv = bias[col];
        const f32x4 a = (ff == 0) ? acc0 : (ff == 1) ? acc1 : (ff == 2) ? acc2 : acc3;
        #pragma unroll
        for (int r = 0; r < 4; ++r) {
            out[(size_t)(rr + r) * N_O + col] = a[r] + bv;
        }
    }
}

extern "C" void kernel_launch(void* const* d_in, const int* in_sizes, int n_in,
                              void* d_out, int out_size, void* d_ws, size_t ws_size,
                              hipStream_t stream) {
    const float* X    = (const float*)d_in[0];   // (32768, 512) f32
    const float* C    = (const float*)d_in[1];   // (2, 512, 64, 8) f32
    const float* bias = (const float*)d_in[2];   // (64,) f32
    float* out = (float*)d_out;                  // (32768, 64) f32

    dim3 grid(N_B / 128);   // 256 blocks, BM=128
    dim3 block(512);        // 8 waves
    fkan_main<<<grid, block, 0, stream>>>(X, C, bias, out);
}

// Round 2
// 139.735 us; speedup vs baseline: 1.6399x; 1.6399x over previous
//
#include <hip/hip_runtime.h>
#include <hip/hip_bf16.h>

// Fourier-KAN, round 2: GEMM M=32768 N=64 K=8192 with on-the-fly A.
//   k = i*16 + t*8 + g   (t=0 cos, t=1 sin; g=freq-1)
// mfma_f32_32x32x16_bf16: A row=lane&31, k=(lane>>5)*8+e; B col=lane&31, same k map
// (A/B slot-symmetric => internal k-permutation cancels). C/D (verified m74/m101):
//   col=lane&31, row=(reg&3)+8*(reg>>2)+4*(lane>>5).
// Block: 512 thr = 8 waves = 8 K-groups (wave q owns i = c*8+q per chunk),
// each wave does 2 M-tiles (64 rows) x 2 N-frags -> 4 accs (64 VGPR).
// Grid 512 (BM=64) -> 2 blocks/CU, 16 waves/CU. LDS 64KB/block.
// Weights pre-packed to bf16 fragment order in d_ws by prep kernel; staged via
// global_load_lds(16B). X staged via coalesced float4 -> LDS, dbuf per 4 chunks.
// End: 3-phase LDS tree reduction over the 8 K-group partials.

#define N_B 32768
#define N_I 512
#define N_O 64

typedef short bf16x8 __attribute__((ext_vector_type(8)));
typedef float f32x4  __attribute__((ext_vector_type(4)));
typedef float f32x16 __attribute__((ext_vector_type(16)));

__device__ __forceinline__ int pack_bf16x2(float lo, float hi) {
    union { __hip_bfloat162 h; int i; } u;
    u.h = __float22bfloat162_rn(make_float2(lo, hi));
    return u.i;
}

// ---------------- prep: C (f32) -> ws (bf16, fragment-ordered) ----------------
// ws 16B-slot [c*1024 + (q*2+f)*64 + l] = bf16( C[t=l>>5][i=c*8+q][n=f*32+(l&31)][g=0..7] )
__global__ __launch_bounds__(256)
void fkan_prep(const float* __restrict__ C, int4* __restrict__ ws) {
    const int tid = blockIdx.x * 256 + threadIdx.x;   // 65536 threads
    const int t = tid >> 15;
    const int i = (tid >> 6) & 511;
    const int n = tid & 63;
    const float* src = C + ((size_t)(t * N_I + i) * N_O + n) * 8;
    const float4 v0 = *(const float4*)(src);
    const float4 v1 = *(const float4*)(src + 4);
    int4 w;
    w.x = pack_bf16x2(v0.x, v0.y);
    w.y = pack_bf16x2(v0.z, v0.w);
    w.z = pack_bf16x2(v1.x, v1.y);
    w.w = pack_bf16x2(v1.z, v1.w);
    const int c = i >> 3, q = i & 7, f = n >> 5, l = t * 32 + (n & 31);
    ws[c * 1024 + (q * 2 + f) * 64 + l] = w;
}

// ---------------- main ----------------
__device__ __forceinline__ void glds16(const void* g, void* lds) {
    __builtin_amdgcn_global_load_lds(
        (const __attribute__((address_space(1))) unsigned int*)g,
        (__attribute__((address_space(3))) unsigned int*)lds, 16, 0, 0);
}

// stage 16KB weight chunk c into Wbuf: lane writes Wbuf + wave*1024 + lane*16
__device__ __forceinline__ void stageW(const int4* __restrict__ Wf,
                                       unsigned char* Wbuf, int c, int tid) {
    const int wv = tid >> 6;
    const int4* s = Wf + c * 1024 + tid;
    glds16(s,       Wbuf + wv * 1024);
    glds16(s + 512, Wbuf + 8192 + wv * 1024);
}

// scatter one float4 of x into Xs[q][row][j] layout (f32 idx = q*256 + row*4 + j)
__device__ __forceinline__ void xs_write(float* Xbuf, int tid, float4 v) {
    const int row = tid >> 3;
    const int j4  = (tid & 7) * 4;
    const float vv[4] = {v.x, v.y, v.z, v.w};
    #pragma unroll
    for (int m = 0; m < 4; ++m) {
        const int iloc = j4 + m;
        Xbuf[(iloc & 7) * 256 + row * 4 + (iloc >> 3)] = vv[m];
    }
}

// branchless cos/sin Chebyshev chain -> packed bf16 A-fragment (freqs 1..8)
__device__ __forceinline__ bf16x8 trigfrag(float x, int h) {
    float s1, c1;
    __sincosf(x, &s1, &c1);
    const float t2 = c1 + c1;
    const float p0 = h ? 0.f : 1.f;
    const float p1 = h ? s1  : c1;
    const float p2 = __builtin_fmaf(t2, p1, -p0);
    const float p3 = __builtin_fmaf(t2, p2, -p1);
    const float p4 = __builtin_fmaf(t2, p3, -p2);
    const float p5 = __builtin_fmaf(t2, p4, -p3);
    const float p6 = __builtin_fmaf(t2, p5, -p4);
    const float p7 = __builtin_fmaf(t2, p6, -p5);
    const float p8 = __builtin_fmaf(t2, p7, -p6);
    union { int d[4]; bf16x8 v; } u;
    u.d[0] = pack_bf16x2(p1, p2);
    u.d[1] = pack_bf16x2(p3, p4);
    u.d[2] = pack_bf16x2(p5, p6);
    u.d[3] = pack_bf16x2(p7, p8);
    return u.v;
}

__device__ __forceinline__ void dumpAcc(float* base, const f32x16* acc, int l) {
    #pragma unroll
    for (int fr = 0; fr < 4; ++fr) {
        union { f32x16 v; f32x4 s[4]; } u; u.v = acc[fr];
        #pragma unroll
        for (int rg = 0; rg < 4; ++rg)
            *(f32x4*)(base + fr * 1024 + rg * 256 + l * 4) = u.s[rg];
    }
}
__device__ __forceinline__ void addAcc(const float* base, f32x16* acc, int l) {
    #pragma unroll
    for (int fr = 0; fr < 4; ++fr) {
        union { f32x16 v; f32x4 s[4]; } u; u.v = acc[fr];
        #pragma unroll
        for (int rg = 0; rg < 4; ++rg)
            u.s[rg] += *(const f32x4*)(base + fr * 1024 + rg * 256 + l * 4);
        acc[fr] = u.v;
    }
}

__global__ __launch_bounds__(512, 4)
void fkan_main(const float* __restrict__ X, const int4* __restrict__ Wf,
               const float* __restrict__ bias, float* __restrict__ out) {
    __shared__ __align__(16) unsigned char smem[65536];
    unsigned char* Wl = smem;                    // 2 x 16KB weight chunks
    float* Xs = (float*)(smem + 32768);          // 2 x 8KB x super-chunks

    const int tid    = threadIdx.x;
    const int l      = tid & 63;
    const int q      = tid >> 6;     // wave id = K-group
    const int h      = l >> 5;       // 0: cos, 1: sin
    const int lane31 = l & 31;
    const int row0   = blockIdx.x * 64;

    const float* xsrc = X + (size_t)(row0 + (tid >> 3)) * N_I + (tid & 7) * 4;

    f32x16 acc[4];
    #pragma unroll
    for (int a = 0; a < 4; ++a)
        #pragma unroll
        for (int r = 0; r < 16; ++r) acc[a][r] = 0.f;

    // ---- prologue: W chunk 0 -> buf0, X super-chunk 0 -> buf0 ----
    stageW(Wf, Wl, 0, tid);
    {
        float4 xv = *(const float4*)xsrc;
        xs_write(Xs, tid, xv);
    }
    __syncthreads();

    f32x4 xa, xb;
    float4 xnext;

    #pragma unroll 1
    for (int sc = 0; sc < 16; ++sc) {
        #pragma unroll
        for (int j = 0; j < 4; ++j) {
            const int c = sc * 4 + j;
            if (j == 0) {
                const float* xs = Xs + ((sc & 1) << 11) + q * 256;
                xa = *(const f32x4*)(xs + lane31 * 4);
                xb = *(const f32x4*)(xs + (32 + lane31) * 4);
            }
            if (c < 63) stageW(Wf, Wl + (((c + 1) & 1) << 14), c + 1, tid);
            if (j == 1 && sc < 15) xnext = *(const float4*)(xsrc + (sc + 1) * 32);
            if (j == 2 && sc < 15) xs_write(Xs + (((sc + 1) & 1) << 11), tid, xnext);

            const bf16x8 A0 = trigfrag(xa[j], h);
            const bf16x8 A1 = trigfrag(xb[j], h);

            const unsigned char* wb = Wl + ((c & 1) << 14) + (q * 2) * 1024 + l * 16;
            const bf16x8 b0 = *(const bf16x8*)(wb);
            const bf16x8 b1 = *(const bf16x8*)(wb + 1024);

            acc[0] = __builtin_amdgcn_mfma_f32_32x32x16_bf16(A0, b0, acc[0], 0, 0, 0);
            acc[1] = __builtin_amdgcn_mfma_f32_32x32x16_bf16(A0, b1, acc[1], 0, 0, 0);
            acc[2] = __builtin_amdgcn_mfma_f32_32x32x16_bf16(A1, b0, acc[2], 0, 0, 0);
            acc[3] = __builtin_amdgcn_mfma_f32_32x32x16_bf16(A1, b1, acc[3], 0, 0, 0);
            __syncthreads();
        }
    }

    // ---- 3-phase tree reduction over K-groups (8 -> 4 -> 2 -> 1) ----
    float* R = (float*)smem;   // 64KB overlay (main buffers dead now)
    if (q >= 4) dumpAcc(R + (q - 4) * 4096, acc, l);
    __syncthreads();
    if (q < 4) addAcc(R + q * 4096, acc, l);
    __syncthreads();
    if (q == 2 || q == 3) dumpAcc(R + (q - 2) * 4096, acc, l);
    __syncthreads();
    if (q < 2) addAcc(R + q * 4096, acc, l);
    __syncthreads();
    if (q == 1) dumpAcc(R, acc, l);
    __syncthreads();
    if (q == 0) {
        addAcc(R, acc, l);
        #pragma unroll
        for (int mt = 0; mt < 2; ++mt) {
            #pragma unroll
            for (int f = 0; f < 2; ++f) {
                const float bv = bias[f * 32 + lane31];
                #pragma unroll
                for (int r = 0; r < 16; ++r) {
                    const int orow = mt * 32 + (r & 3) + 8 * (r >> 2) + 4 * h;
                    out[(size_t)(row0 + orow) * N_O + f * 32 + lane31] =
                        acc[mt * 2 + f][r] + bv;
                }
            }
        }
    }
}

extern "C" void kernel_launch(void* const* d_in, const int* in_sizes, int n_in,
                              void* d_out, int out_size, void* d_ws, size_t ws_size,
                              hipStream_t stream) {
    const float* X    = (const float*)d_in[0];   // (32768, 512) f32
    const float* C    = (const float*)d_in[1];   // (2, 512, 64, 8) f32
    const float* bias = (const float*)d_in[2];   // (64,) f32
    float* out = (float*)d_out;                  // (32768, 64) f32
    int4* ws = (int4*)d_ws;                      // 1 MB bf16 fragment-ordered weights

    fkan_prep<<<256, 256, 0, stream>>>(C, ws);
    fkan_main<<<512, 512, 0, stream>>>(X, ws, bias, out);
}

// Round 3
// 138.884 us; speedup vs baseline: 1.6500x; 1.0061x over previous
//
#include <hip/hip_runtime.h>
#include <hip/hip_bf16.h>

// Fourier-KAN, round 3: GEMM M=32768 N=64 K=8192 with on-the-fly A.
// Same math/layout as round 2 (verified absmax 0.031):
//   k = i*16 + t*8 + g; mfma_f32_32x32x16_bf16; A/B slot-symmetric k map;
//   C/D col=lane&31, row=(reg&3)+8*(reg>>2)+4*(lane>>5).
// NEW: counted-vmcnt pipeline (T3/T4) — depth-3 W prefetch through 4 LDS
// buffers, raw s_barrier + s_waitcnt vmcnt(N) (never 0 in steady state),
// X float4 prefetch pinned by asm memory fences so the vmcnt ledger is exact.
// Steady N per j = [5,5,5,4]. Native v_sin/v_cos. setprio(1) around MFMAs.

#define N_B 32768
#define N_I 512
#define N_O 64

typedef short bf16x8 __attribute__((ext_vector_type(8)));
typedef float f32x4  __attribute__((ext_vector_type(4)));
typedef float f32x16 __attribute__((ext_vector_type(16)));

__device__ __forceinline__ int pack_bf16x2(float lo, float hi) {
    union { __hip_bfloat162 h; int i; } u;
    u.h = __float22bfloat162_rn(make_float2(lo, hi));
    return u.i;
}

#define FENCE() asm volatile("" ::: "memory")

template<int NWAIT>
__device__ __forceinline__ void waitb() {
    asm volatile("s_waitcnt vmcnt(%0) lgkmcnt(0)" :: "n"(NWAIT) : "memory");
    __builtin_amdgcn_s_barrier();
    __builtin_amdgcn_sched_barrier(0);
}

// ---------------- prep: C (f32) -> ws (bf16, fragment-ordered) ----------------
// ws 16B-slot [c*1024 + (q*2+f)*64 + l] = bf16( C[t=l>>5][i=c*8+q][n=f*32+(l&31)][g=0..7] )
__global__ __launch_bounds__(256)
void fkan_prep(const float* __restrict__ C, int4* __restrict__ ws) {
    const int tid = blockIdx.x * 256 + threadIdx.x;   // 65536 threads
    const int t = tid >> 15;
    const int i = (tid >> 6) & 511;
    const int n = tid & 63;
    const float* src = C + ((size_t)(t * N_I + i) * N_O + n) * 8;
    const float4 v0 = *(const float4*)(src);
    const float4 v1 = *(const float4*)(src + 4);
    int4 w;
    w.x = pack_bf16x2(v0.x, v0.y);
    w.y = pack_bf16x2(v0.z, v0.w);
    w.z = pack_bf16x2(v1.x, v1.y);
    w.w = pack_bf16x2(v1.z, v1.w);
    const int c = i >> 3, q = i & 7, f = n >> 5, l = t * 32 + (n & 31);
    ws[c * 1024 + (q * 2 + f) * 64 + l] = w;
}

// ---------------- main ----------------
__device__ __forceinline__ void glds16(const void* g, void* lds) {
    __builtin_amdgcn_global_load_lds(
        (const __attribute__((address_space(1))) unsigned int*)g,
        (__attribute__((address_space(3))) unsigned int*)lds, 16, 0, 0);
}

// stage 16KB weight chunk c into Wbuf: wave wv's lanes land at Wbuf+wv*1024+lane*16
__device__ __forceinline__ void stageW(const int4* __restrict__ Wf,
                                       unsigned char* Wbuf, int c, int tid) {
    const int wv = tid >> 6;
    const int4* s = Wf + c * 1024 + tid;
    glds16(s,       Wbuf + wv * 1024);
    glds16(s + 512, Wbuf + 8192 + wv * 1024);
}

// scatter one float4 of x into Xs[q][row][j] layout (f32 idx = q*256 + row*4 + j)
__device__ __forceinline__ void xs_write(float* Xbuf, int tid, float4 v) {
    const int row = tid >> 3;
    const int j4  = (tid & 7) * 4;
    const float vv[4] = {v.x, v.y, v.z, v.w};
    #pragma unroll
    for (int m = 0; m < 4; ++m) {
        const int iloc = j4 + m;
        Xbuf[(iloc & 7) * 256 + row * 4 + (iloc >> 3)] = vv[m];
    }
}

// branchless cos/sin Chebyshev chain -> packed bf16 A-fragment (freqs 1..8)
__device__ __forceinline__ bf16x8 trigfrag(float x, int h) {
    const float r  = x * 0.15915494309189535f;   // revolutions
    const float s1 = __builtin_amdgcn_sinf(r);
    const float c1 = __builtin_amdgcn_cosf(r);
    const float t2 = c1 + c1;
    const float p0 = h ? 0.f : 1.f;
    const float p1 = h ? s1  : c1;
    const float p2 = __builtin_fmaf(t2, p1, -p0);
    const float p3 = __builtin_fmaf(t2, p2, -p1);
    const float p4 = __builtin_fmaf(t2, p3, -p2);
    const float p5 = __builtin_fmaf(t2, p4, -p3);
    const float p6 = __builtin_fmaf(t2, p5, -p4);
    const float p7 = __builtin_fmaf(t2, p6, -p5);
    const float p8 = __builtin_fmaf(t2, p7, -p6);
    union { int d[4]; bf16x8 v; } u;
    u.d[0] = pack_bf16x2(p1, p2);
    u.d[1] = pack_bf16x2(p3, p4);
    u.d[2] = pack_bf16x2(p5, p6);
    u.d[3] = pack_bf16x2(p7, p8);
    return u.v;
}

// one K-step: read 2 B-frags from W buffer J, build 2 A-frags, 4 MFMAs
template<int J>
__device__ __forceinline__ void compute4(const unsigned char* Wl, int qoff, int h,
                                         float xaj, float xbj, f32x16* acc) {
    const unsigned char* wb = Wl + J * 16384 + qoff;
    const bf16x8 b0 = *(const bf16x8*)(wb);
    const bf16x8 b1 = *(const bf16x8*)(wb + 1024);
    const bf16x8 A0 = trigfrag(xaj, h);
    const bf16x8 A1 = trigfrag(xbj, h);
    __builtin_amdgcn_s_setprio(1);
    acc[0] = __builtin_amdgcn_mfma_f32_32x32x16_bf16(A0, b0, acc[0], 0, 0, 0);
    acc[1] = __builtin_amdgcn_mfma_f32_32x32x16_bf16(A0, b1, acc[1], 0, 0, 0);
    acc[2] = __builtin_amdgcn_mfma_f32_32x32x16_bf16(A1, b0, acc[2], 0, 0, 0);
    acc[3] = __builtin_amdgcn_mfma_f32_32x32x16_bf16(A1, b1, acc[3], 0, 0, 0);
    __builtin_amdgcn_s_setprio(0);
}

__device__ __forceinline__ void dumpAcc(float* base, const f32x16* acc, int l) {
    #pragma unroll
    for (int fr = 0; fr < 4; ++fr) {
        union { f32x16 v; f32x4 s[4]; } u; u.v = acc[fr];
        #pragma unroll
        for (int rg = 0; rg < 4; ++rg)
            *(f32x4*)(base + fr * 1024 + rg * 256 + l * 4) = u.s[rg];
    }
}
__device__ __forceinline__ void addAcc(const float* base, f32x16* acc, int l) {
    #pragma unroll
    for (int fr = 0; fr < 4; ++fr) {
        union { f32x16 v; f32x4 s[4]; } u; u.v = acc[fr];
        #pragma unroll
        for (int rg = 0; rg < 4; ++rg)
            u.s[rg] += *(const f32x4*)(base + fr * 1024 + rg * 256 + l * 4);
        acc[fr] = u.v;
    }
}

__global__ __launch_bounds__(512, 4)
void fkan_main(const float* __restrict__ X, const int4* __restrict__ Wf,
               const float* __restrict__ bias, float* __restrict__ out) {
    __shared__ __align__(16) unsigned char smem[81920];
    unsigned char* Wl = smem;                    // 4 x 16KB weight chunk buffers
    float* Xs = (float*)(smem + 65536);          // 2 x 8KB x super-chunks

    const int tid    = threadIdx.x;
    const int l      = tid & 63;
    const int q      = tid >> 6;     // wave id = K-group
    const int h      = l >> 5;       // 0: cos, 1: sin
    const int lane31 = l & 31;
    const int row0   = blockIdx.x * 64;
    const int qoff   = q * 2048 + l * 16;

    const float* xsrc = X + (size_t)(row0 + (tid >> 3)) * N_I + (tid & 7) * 4;

    f32x16 acc[4];
    #pragma unroll
    for (int a = 0; a < 4; ++a)
        #pragma unroll
        for (int r = 0; r < 16; ++r) acc[a][r] = 0.f;

    // ---- prologue: X super-chunk 0 -> buf0 (regs->LDS), W chunks 0..2 ----
    {
        float4 x0 = *(const float4*)xsrc;
        xs_write(Xs, tid, x0);
    }
    stageW(Wf, Wl,             0, tid);
    stageW(Wf, Wl + 16384,     1, tid);
    stageW(Wf, Wl + 2 * 16384, 2, tid);
    FENCE();
    waitb<4>();   // W0 complete (W1,W2 in flight)

    float4 xnext;

    // ---- steady loop: sc = 0..14, chunk k = 4sc+j uses W buffer j ----
    #pragma unroll 1
    for (int sc = 0; sc < 15; ++sc) {
        const int k0 = sc * 4;
        const float* xsb = Xs + ((sc & 1) << 11) + q * 256;
        const f32x4 xa = *(const f32x4*)(xsb + lane31 * 4);
        const f32x4 xb = *(const f32x4*)(xsb + (32 + lane31) * 4);

        // j = 0: stage W(k0+3)->buf3, issue X(sc+1)
        compute4<0>(Wl, qoff, h, xa[0], xb[0], acc);
        stageW(Wf, Wl + 3 * 16384, k0 + 3, tid);
        FENCE();
        xnext = *(const float4*)(xsrc + (sc + 1) * 32);
        FENCE();
        waitb<5>();

        // j = 1: stage W(k0+4)->buf0
        compute4<1>(Wl, qoff, h, xa[1], xb[1], acc);
        stageW(Wf, Wl, k0 + 4, tid);
        FENCE();
        waitb<5>();

        // j = 2: stage W(k0+5)->buf1
        compute4<2>(Wl, qoff, h, xa[2], xb[2], acc);
        stageW(Wf, Wl + 16384, k0 + 5, tid);
        FENCE();
        waitb<5>();

        // j = 3: stage W(k0+6)->buf2, scatter X(sc+1) into its LDS buffer
        compute4<3>(Wl, qoff, h, xa[3], xb[3], acc);
        stageW(Wf, Wl + 2 * 16384, k0 + 6, tid);
        FENCE();
        xs_write(Xs + (((sc + 1) & 1) << 11), tid, xnext);
        waitb<4>();
    }

    // ---- peeled last super-chunk (sc = 15, chunks 60..63) ----
    {
        const float* xsb = Xs + (1 << 11) + q * 256;
        const f32x4 xa = *(const f32x4*)(xsb + lane31 * 4);
        const f32x4 xb = *(const f32x4*)(xsb + (32 + lane31) * 4);

        compute4<0>(Wl, qoff, h, xa[0], xb[0], acc);
        stageW(Wf, Wl + 3 * 16384, 63, tid);
        FENCE();
        waitb<4>();

        compute4<1>(Wl, qoff, h, xa[1], xb[1], acc);
        waitb<2>();

        compute4<2>(Wl, qoff, h, xa[2], xb[2], acc);
        waitb<0>();

        compute4<3>(Wl, qoff, h, xa[3], xb[3], acc);
    }
    __syncthreads();

    // ---- 3-phase tree reduction over K-groups (8 -> 4 -> 2 -> 1) ----
    float* R = (float*)smem;   // 64KB overlay (main buffers dead now)
    if (q >= 4) dumpAcc(R + (q - 4) * 4096, acc, l);
    __syncthreads();
    if (q < 4) addAcc(R + q * 4096, acc, l);
    __syncthreads();
    if (q == 2 || q == 3) dumpAcc(R + (q - 2) * 4096, acc, l);
    __syncthreads();
    if (q < 2) addAcc(R + q * 4096, acc, l);
    __syncthreads();
    if (q == 1) dumpAcc(R, acc, l);
    __syncthreads();
    if (q == 0) {
        addAcc(R, acc, l);
        #pragma unroll
        for (int mt = 0; mt < 2; ++mt) {
            #pragma unroll
            for (int f = 0; f < 2; ++f) {
                const float bv = bias[f * 32 + lane31];
                #pragma unroll
                for (int r = 0; r < 16; ++r) {
                    const int orow = mt * 32 + (r & 3) + 8 * (r >> 2) + 4 * h;
                    out[(size_t)(row0 + orow) * N_O + f * 32 + lane31] =
                        acc[mt * 2 + f][r] + bv;
                }
            }
        }
    }
}

extern "C" void kernel_launch(void* const* d_in, const int* in_sizes, int n_in,
                              void* d_out, int out_size, void* d_ws, size_t ws_size,
                              hipStream_t stream) {
    const float* X    = (const float*)d_in[0];   // (32768, 512) f32
    const float* C    = (const float*)d_in[1];   // (2, 512, 64, 8) f32
    const float* bias = (const float*)d_in[2];   // (64,) f32
    float* out = (float*)d_out;                  // (32768, 64) f32
    int4* ws = (int4*)d_ws;                      // 1 MB bf16 fragment-ordered weights

    fkan_prep<<<256, 256, 0, stream>>>(C, ws);
    fkan_main<<<512, 512, 0, stream>>>(X, ws, bias, out);
}

// Round 4
// 130.748 us; speedup vs baseline: 1.7527x; 1.0622x over previous
//
#include <hip/hip_runtime.h>
#include <hip/hip_bf16.h>

// Fourier-KAN, round 4: GEMM M=32768 N=64 K=8192 with on-the-fly A.
// Same math/layout as rounds 2-3 (verified absmax 0.031):
//   k = i*16 + t*8 + g; mfma_f32_32x32x16_bf16; A/B slot-symmetric k map;
//   C/D col=lane&31, row=(reg&3)+8*(reg>>2)+4*(lane>>5).
// Counted-vmcnt pipeline (T3/T4) unchanged from round 3.
// NEW: f32->bf16 packing via inline-asm v_cvt_pk_bf16_f32 (1 instr / pair)
// instead of __float22bfloat162_rn's software RNE (~5-6 VALU per float).
// Theory: round-3 counters show ~145 VALU instr/wave/chunk vs ~50 intended;
// the excess is the software bf16 conversion. This was the VALU bound.

#define N_B 32768
#define N_I 512
#define N_O 64

typedef short bf16x8 __attribute__((ext_vector_type(8)));
typedef float f32x4  __attribute__((ext_vector_type(4)));
typedef float f32x16 __attribute__((ext_vector_type(16)));

// hardware packed f32->bf16 (RNE): dst.lo = bf16(lo), dst.hi = bf16(hi)
__device__ __forceinline__ int cvtpk(float lo, float hi) {
    int r;
    asm("v_cvt_pk_bf16_f32 %0, %1, %2" : "=v"(r) : "v"(lo), "v"(hi));
    return r;
}

#define FENCE() asm volatile("" ::: "memory")

template<int NWAIT>
__device__ __forceinline__ void waitb() {
    asm volatile("s_waitcnt vmcnt(%0) lgkmcnt(0)" :: "n"(NWAIT) : "memory");
    __builtin_amdgcn_s_barrier();
    __builtin_amdgcn_sched_barrier(0);
}

// ---------------- prep: C (f32) -> ws (bf16, fragment-ordered) ----------------
// ws 16B-slot [c*1024 + (q*2+f)*64 + l] = bf16( C[t=l>>5][i=c*8+q][n=f*32+(l&31)][g=0..7] )
__global__ __launch_bounds__(256)
void fkan_prep(const float* __restrict__ C, int4* __restrict__ ws) {
    const int tid = blockIdx.x * 256 + threadIdx.x;   // 65536 threads
    const int t = tid >> 15;
    const int i = (tid >> 6) & 511;
    const int n = tid & 63;
    const float* src = C + ((size_t)(t * N_I + i) * N_O + n) * 8;
    const float4 v0 = *(const float4*)(src);
    const float4 v1 = *(const float4*)(src + 4);
    int4 w;
    w.x = cvtpk(v0.x, v0.y);
    w.y = cvtpk(v0.z, v0.w);
    w.z = cvtpk(v1.x, v1.y);
    w.w = cvtpk(v1.z, v1.w);
    const int c = i >> 3, q = i & 7, f = n >> 5, l = t * 32 + (n & 31);
    ws[c * 1024 + (q * 2 + f) * 64 + l] = w;
}

// ---------------- main ----------------
__device__ __forceinline__ void glds16(const void* g, void* lds) {
    __builtin_amdgcn_global_load_lds(
        (const __attribute__((address_space(1))) unsigned int*)g,
        (__attribute__((address_space(3))) unsigned int*)lds, 16, 0, 0);
}

// stage 16KB weight chunk c into Wbuf: wave wv's lanes land at Wbuf+wv*1024+lane*16
__device__ __forceinline__ void stageW(const int4* __restrict__ Wf,
                                       unsigned char* Wbuf, int c, int tid) {
    const int wv = tid >> 6;
    const int4* s = Wf + c * 1024 + tid;
    glds16(s,       Wbuf + wv * 1024);
    glds16(s + 512, Wbuf + 8192 + wv * 1024);
}

// scatter one float4 of x into Xs[q][row][j] layout (f32 idx = q*256 + row*4 + j)
__device__ __forceinline__ void xs_write(float* Xbuf, int tid, float4 v) {
    const int row = tid >> 3;
    const int j4  = (tid & 7) * 4;
    const float vv[4] = {v.x, v.y, v.z, v.w};
    #pragma unroll
    for (int m = 0; m < 4; ++m) {
        const int iloc = j4 + m;
        Xbuf[(iloc & 7) * 256 + row * 4 + (iloc >> 3)] = vv[m];
    }
}

// branchless cos/sin Chebyshev chain -> packed bf16 A-fragment (freqs 1..8)
__device__ __forceinline__ bf16x8 trigfrag(float x, int h) {
    const float r  = x * 0.15915494309189535f;   // revolutions
    const float s1 = __builtin_amdgcn_sinf(r);
    const float c1 = __builtin_amdgcn_cosf(r);
    const float t2 = c1 + c1;
    const float p0 = h ? 0.f : 1.f;
    const float p1 = h ? s1  : c1;
    const float p2 = __builtin_fmaf(t2, p1, -p0);
    const float p3 = __builtin_fmaf(t2, p2, -p1);
    const float p4 = __builtin_fmaf(t2, p3, -p2);
    const float p5 = __builtin_fmaf(t2, p4, -p3);
    const float p6 = __builtin_fmaf(t2, p5, -p4);
    const float p7 = __builtin_fmaf(t2, p6, -p5);
    const float p8 = __builtin_fmaf(t2, p7, -p6);
    union { int d[4]; bf16x8 v; } u;
    u.d[0] = cvtpk(p1, p2);
    u.d[1] = cvtpk(p3, p4);
    u.d[2] = cvtpk(p5, p6);
    u.d[3] = cvtpk(p7, p8);
    return u.v;
}

// one K-step: read 2 B-frags from W buffer J, build 2 A-frags, 4 MFMAs
template<int J>
__device__ __forceinline__ void compute4(const unsigned char* Wl, int qoff, int h,
                                         float xaj, float xbj, f32x16* acc) {
    const unsigned char* wb = Wl + J * 16384 + qoff;
    const bf16x8 b0 = *(const bf16x8*)(wb);
    const bf16x8 b1 = *(const bf16x8*)(wb + 1024);
    const bf16x8 A0 = trigfrag(xaj, h);
    const bf16x8 A1 = trigfrag(xbj, h);
    __builtin_amdgcn_s_setprio(1);
    acc[0] = __builtin_amdgcn_mfma_f32_32x32x16_bf16(A0, b0, acc[0], 0, 0, 0);
    acc[1] = __builtin_amdgcn_mfma_f32_32x32x16_bf16(A0, b1, acc[1], 0, 0, 0);
    acc[2] = __builtin_amdgcn_mfma_f32_32x32x16_bf16(A1, b0, acc[2], 0, 0, 0);
    acc[3] = __builtin_amdgcn_mfma_f32_32x32x16_bf16(A1, b1, acc[3], 0, 0, 0);
    __builtin_amdgcn_s_setprio(0);
}

__device__ __forceinline__ void dumpAcc(float* base, const f32x16* acc, int l) {
    #pragma unroll
    for (int fr = 0; fr < 4; ++fr) {
        union { f32x16 v; f32x4 s[4]; } u; u.v = acc[fr];
        #pragma unroll
        for (int rg = 0; rg < 4; ++rg)
            *(f32x4*)(base + fr * 1024 + rg * 256 + l * 4) = u.s[rg];
    }
}
__device__ __forceinline__ void addAcc(const float* base, f32x16* acc, int l) {
    #pragma unroll
    for (int fr = 0; fr < 4; ++fr) {
        union { f32x16 v; f32x4 s[4]; } u; u.v = acc[fr];
        #pragma unroll
        for (int rg = 0; rg < 4; ++rg)
            u.s[rg] += *(const f32x4*)(base + fr * 1024 + rg * 256 + l * 4);
        acc[fr] = u.v;
    }
}

__global__ __launch_bounds__(512, 4)
void fkan_main(const float* __restrict__ X, const int4* __restrict__ Wf,
               const float* __restrict__ bias, float* __restrict__ out) {
    __shared__ __align__(16) unsigned char smem[81920];
    unsigned char* Wl = smem;                    // 4 x 16KB weight chunk buffers
    float* Xs = (float*)(smem + 65536);          // 2 x 8KB x super-chunks

    const int tid    = threadIdx.x;
    const int l      = tid & 63;
    const int q      = tid >> 6;     // wave id = K-group
    const int h      = l >> 5;       // 0: cos, 1: sin
    const int lane31 = l & 31;
    const int row0   = blockIdx.x * 64;
    const int qoff   = q * 2048 + l * 16;

    const float* xsrc = X + (size_t)(row0 + (tid >> 3)) * N_I + (tid & 7) * 4;

    f32x16 acc[4];
    #pragma unroll
    for (int a = 0; a < 4; ++a)
        #pragma unroll
        for (int r = 0; r < 16; ++r) acc[a][r] = 0.f;

    // ---- prologue: X super-chunk 0 -> buf0 (regs->LDS), W chunks 0..2 ----
    {
        float4 x0 = *(const float4*)xsrc;
        xs_write(Xs, tid, x0);
    }
    stageW(Wf, Wl,             0, tid);
    stageW(Wf, Wl + 16384,     1, tid);
    stageW(Wf, Wl + 2 * 16384, 2, tid);
    FENCE();
    waitb<4>();   // W0 complete (W1,W2 in flight)

    float4 xnext;

    // ---- steady loop: sc = 0..14, chunk k = 4sc+j uses W buffer j ----
    #pragma unroll 1
    for (int sc = 0; sc < 15; ++sc) {
        const int k0 = sc * 4;
        const float* xsb = Xs + ((sc & 1) << 11) + q * 256;
        const f32x4 xa = *(const f32x4*)(xsb + lane31 * 4);
        const f32x4 xb = *(const f32x4*)(xsb + (32 + lane31) * 4);

        // j = 0: stage W(k0+3)->buf3, issue X(sc+1)
        compute4<0>(Wl, qoff, h, xa[0], xb[0], acc);
        stageW(Wf, Wl + 3 * 16384, k0 + 3, tid);
        FENCE();
        xnext = *(const float4*)(xsrc + (sc + 1) * 32);
        FENCE();
        waitb<5>();

        // j = 1: stage W(k0+4)->buf0
        compute4<1>(Wl, qoff, h, xa[1], xb[1], acc);
        stageW(Wf, Wl, k0 + 4, tid);
        FENCE();
        waitb<5>();

        // j = 2: stage W(k0+5)->buf1
        compute4<2>(Wl, qoff, h, xa[2], xb[2], acc);
        stageW(Wf, Wl + 16384, k0 + 5, tid);
        FENCE();
        waitb<5>();

        // j = 3: stage W(k0+6)->buf2, scatter X(sc+1) into its LDS buffer
        compute4<3>(Wl, qoff, h, xa[3], xb[3], acc);
        stageW(Wf, Wl + 2 * 16384, k0 + 6, tid);
        FENCE();
        xs_write(Xs + (((sc + 1) & 1) << 11), tid, xnext);
        waitb<4>();
    }

    // ---- peeled last super-chunk (sc = 15, chunks 60..63) ----
    {
        const float* xsb = Xs + (1 << 11) + q * 256;
        const f32x4 xa = *(const f32x4*)(xsb + lane31 * 4);
        const f32x4 xb = *(const f32x4*)(xsb + (32 + lane31) * 4);

        compute4<0>(Wl, qoff, h, xa[0], xb[0], acc);
        stageW(Wf, Wl + 3 * 16384, 63, tid);
        FENCE();
        waitb<4>();

        compute4<1>(Wl, qoff, h, xa[1], xb[1], acc);
        waitb<2>();

        compute4<2>(Wl, qoff, h, xa[2], xb[2], acc);
        waitb<0>();

        compute4<3>(Wl, qoff, h, xa[3], xb[3], acc);
    }
    __syncthreads();

    // ---- 3-phase tree reduction over K-groups (8 -> 4 -> 2 -> 1) ----
    float* R = (float*)smem;   // 64KB overlay (main buffers dead now)
    if (q >= 4) dumpAcc(R + (q - 4) * 4096, acc, l);
    __syncthreads();
    if (q < 4) addAcc(R + q * 4096, acc, l);
    __syncthreads();
    if (q == 2 || q == 3) dumpAcc(R + (q - 2) * 4096, acc, l);
    __syncthreads();
    if (q < 2) addAcc(R + q * 4096, acc, l);
    __syncthreads();
    if (q == 1) dumpAcc(R, acc, l);
    __syncthreads();
    if (q == 0) {
        addAcc(R, acc, l);
        #pragma unroll
        for (int mt = 0; mt < 2; ++mt) {
            #pragma unroll
            for (int f = 0; f < 2; ++f) {
                const float bv = bias[f * 32 + lane31];
                #pragma unroll
                for (int r = 0; r < 16; ++r) {
                    const int orow = mt * 32 + (r & 3) + 8 * (r >> 2) + 4 * h;
                    out[(size_t)(row0 + orow) * N_O + f * 32 + lane31] =
                        acc[mt * 2 + f][r] + bv;
                }
            }
        }
    }
}

extern "C" void kernel_launch(void* const* d_in, const int* in_sizes, int n_in,
                              void* d_out, int out_size, void* d_ws, size_t ws_size,
                              hipStream_t stream) {
    const float* X    = (const float*)d_in[0];   // (32768, 512) f32
    const float* C    = (const float*)d_in[1];   // (2, 512, 64, 8) f32
    const float* bias = (const float*)d_in[2];   // (64,) f32
    float* out = (float*)d_out;                  // (32768, 64) f32
    int4* ws = (int4*)d_ws;                      // 1 MB bf16 fragment-ordered weights

    fkan_prep<<<256, 256, 0, stream>>>(C, ws);
    fkan_main<<<512, 512, 0, stream>>>(X, ws, bias, out);
}